// Round 1
// baseline (1485.210 us; speedup 1.0000x reference)
//
#include <hip/hip_runtime.h>

// Problem constants (fixed by the reference)
static constexpr int NN = 100000;   // nodes
static constexpr int NE = 3200000;  // edges
static constexpr int KF = 512;      // NFEAT
static constexpr int NH = 256;      // NHID
static constexpr int NC = 64;       // NCLASS
static constexpr int NP = 128;      // PROJ

typedef __attribute__((ext_vector_type(4))) float f32x4;
typedef __attribute__((ext_vector_type(8))) __bf16 bf16x8;

__device__ __forceinline__ unsigned short f2bf(float f) {
  unsigned u = __builtin_bit_cast(unsigned, f);
  u += 0x7fffu + ((u >> 16) & 1u);   // RTNE
  return (unsigned short)(u >> 16);
}
__device__ __forceinline__ float bf2f(unsigned short h) {
  return __builtin_bit_cast(float, (unsigned)h << 16);
}

// ---------------------------------------------------------------------------
// CSR build: histogram -> 3-pass exclusive scan -> scatter (col,val) by row
// ---------------------------------------------------------------------------
__global__ void hist_k(const int* __restrict__ rows, int* __restrict__ cnt) {
  int stride = gridDim.x * blockDim.x;
  for (int e = blockIdx.x * blockDim.x + threadIdx.x; e < NE; e += stride)
    atomicAdd(&cnt[rows[e]], 1);
}

// 1024 elements per block, 4 per thread
__global__ __launch_bounds__(256) void scanA_k(const int* __restrict__ cnt,
                                               int* __restrict__ partial,
                                               int* __restrict__ bsums) {
  __shared__ int ts[256];
  const int t = threadIdx.x;
  const int base = blockIdx.x * 1024 + t * 4;
  int v[4]; int s = 0;
#pragma unroll
  for (int j = 0; j < 4; j++) { v[j] = (base + j < NN) ? cnt[base + j] : 0; s += v[j]; }
  ts[t] = s; __syncthreads();
  for (int off = 1; off < 256; off <<= 1) {
    int x2 = (t >= off) ? ts[t - off] : 0;
    __syncthreads();
    ts[t] += x2;
    __syncthreads();
  }
  int excl = ts[t] - s;
#pragma unroll
  for (int j = 0; j < 4; j++) {
    if (base + j < NN) partial[base + j] = excl;
    excl += v[j];
  }
  if (t == 255) bsums[blockIdx.x] = ts[255];
}

__global__ __launch_bounds__(128) void scanB_k(const int* __restrict__ bsums,
                                               int* __restrict__ offs, int nb) {
  __shared__ int ts[128];
  const int t = threadIdx.x;
  int v = (t < nb) ? bsums[t] : 0;
  ts[t] = v; __syncthreads();
  for (int off = 1; off < 128; off <<= 1) {
    int x2 = (t >= off) ? ts[t - off] : 0;
    __syncthreads();
    ts[t] += x2;
    __syncthreads();
  }
  if (t < nb) offs[t] = ts[t] - v;
}

__global__ __launch_bounds__(256) void scanC_k(int* __restrict__ row_ptr,
                                               int* __restrict__ cursor,
                                               const int* __restrict__ offs) {
  const int t = threadIdx.x;
  const int base = blockIdx.x * 1024 + t * 4;
  const int off = offs[blockIdx.x];
#pragma unroll
  for (int j = 0; j < 4; j++) {
    if (base + j < NN) {
      int vv = row_ptr[base + j] + off;
      row_ptr[base + j] = vv;
      cursor[base + j] = vv;
    }
  }
  if (blockIdx.x == 0 && t == 0) row_ptr[NN] = NE;
}

__global__ void scatter_k(const int* __restrict__ rows, const int* __restrict__ cols,
                          const float* __restrict__ vals, int* __restrict__ cur,
                          int* __restrict__ col_s, float* __restrict__ val_s) {
  int stride = gridDim.x * blockDim.x;
  for (int e = blockIdx.x * blockDim.x + threadIdx.x; e < NE; e += stride) {
    int pos = atomicAdd(&cur[rows[e]], 1);
    col_s[pos] = cols[e];
    val_s[pos] = vals[e];
  }
}

// ---------------------------------------------------------------------------
// GEMM1: t1 = x @ W1  (fp32 in, bf16 out), MFMA 16x16x32_bf16
// Block: 256 thr = 4 waves (2m x 2n), tile 128x128, BK=64, K=512
// ---------------------------------------------------------------------------
__global__ __launch_bounds__(256) void gemm1_mfma(const float* __restrict__ x,
                                                  const float* __restrict__ W1,
                                                  unsigned short* __restrict__ t1b) {
  constexpr int LDA = 72;  // 64 + 8 pad (16B-aligned rows, 2-way bank alias = free)
  __shared__ unsigned short As[128 * LDA];
  __shared__ unsigned short Bs[128 * LDA];
  const int tid = threadIdx.x;
  const int m0 = blockIdx.x * 128;
  const int n0 = blockIdx.y * 128;
  const int w = tid >> 6, lane = tid & 63;
  const int wm = w & 1, wn = w >> 1;
  const int quad = lane >> 4, l16 = lane & 15;

  f32x4 acc[4][4] = {};

  for (int ks = 0; ks < 8; ks++) {
    __syncthreads();
    // stage A tile (128 rows x 64 k), fp32 -> bf16
#pragma unroll
    for (int i = 0; i < 8; i++) {
      int it = tid + 256 * i;       // 0..2047
      int row = it >> 4;            // 0..127
      int k4 = (it & 15) * 4;       // 0..60
      int gr = m0 + row; if (gr > NN - 1) gr = NN - 1;
      const float4 v = *(const float4*)(x + (size_t)gr * KF + ks * 64 + k4);
      unsigned lo = (unsigned)f2bf(v.x) | ((unsigned)f2bf(v.y) << 16);
      unsigned hi = (unsigned)f2bf(v.z) | ((unsigned)f2bf(v.w) << 16);
      *(uint2*)&As[row * LDA + k4] = make_uint2(lo, hi);
    }
    // stage B tile transposed: Bs[n][k]
#pragma unroll
    for (int i = 0; i < 8; i++) {
      int it = tid + 256 * i;       // 0..2047
      int n = it & 127;
      int k4 = (it >> 7) * 4;       // 0..60
      int gk = ks * 64 + k4;
      float v0 = W1[(size_t)(gk + 0) * NH + n0 + n];
      float v1 = W1[(size_t)(gk + 1) * NH + n0 + n];
      float v2 = W1[(size_t)(gk + 2) * NH + n0 + n];
      float v3 = W1[(size_t)(gk + 3) * NH + n0 + n];
      unsigned lo = (unsigned)f2bf(v0) | ((unsigned)f2bf(v1) << 16);
      unsigned hi = (unsigned)f2bf(v2) | ((unsigned)f2bf(v3) << 16);
      *(uint2*)&Bs[n * LDA + k4] = make_uint2(lo, hi);
    }
    __syncthreads();
#pragma unroll
    for (int kk = 0; kk < 2; kk++) {
      bf16x8 a[4], b[4];
#pragma unroll
      for (int mt = 0; mt < 4; mt++) {
        const uint4 q = *(const uint4*)&As[(wm * 64 + mt * 16 + l16) * LDA + kk * 32 + quad * 8];
        a[mt] = __builtin_bit_cast(bf16x8, q);
      }
#pragma unroll
      for (int nt = 0; nt < 4; nt++) {
        const uint4 q = *(const uint4*)&Bs[(wn * 64 + nt * 16 + l16) * LDA + kk * 32 + quad * 8];
        b[nt] = __builtin_bit_cast(bf16x8, q);
      }
#pragma unroll
      for (int mt = 0; mt < 4; mt++)
#pragma unroll
        for (int nt = 0; nt < 4; nt++)
          acc[mt][nt] = __builtin_amdgcn_mfma_f32_16x16x32_bf16(a[mt], b[nt], acc[mt][nt], 0, 0, 0);
    }
  }
  // epilogue: C/D layout col=lane&15, row=quad*4+reg
#pragma unroll
  for (int mt = 0; mt < 4; mt++) {
#pragma unroll
    for (int reg = 0; reg < 4; reg++) {
      int row = m0 + wm * 64 + mt * 16 + quad * 4 + reg;
      if (row < NN) {
#pragma unroll
        for (int nt = 0; nt < 4; nt++) {
          int col = n0 + wn * 64 + nt * 16 + l16;
          t1b[(size_t)row * NH + col] = f2bf(acc[mt][nt][reg]);
        }
      }
    }
  }
}

// ---------------------------------------------------------------------------
// spmm1: h = relu(spmm(t1) + b1), CSR, one wave per row, 4 cols/lane (uint2)
// ---------------------------------------------------------------------------
__global__ __launch_bounds__(256) void spmm1_relu(const unsigned short* __restrict__ t1b,
                                                  const float* __restrict__ val_s,
                                                  const int* __restrict__ col_s,
                                                  const int* __restrict__ row_ptr,
                                                  const float* __restrict__ b1,
                                                  unsigned short* __restrict__ hb) {
  const int w = threadIdx.x >> 6, lane = threadIdx.x & 63;
  const int r = blockIdx.x * 4 + w;
  int s = row_ptr[r], e = row_ptr[r + 1];
  s = __builtin_amdgcn_readfirstlane(s);
  e = __builtin_amdgcn_readfirstlane(e);
  float a0 = 0.f, a1 = 0.f, a2 = 0.f, a3 = 0.f;
  for (int i = s; i < e; i++) {
    const float v = val_s[i];
    const int c = col_s[i];
    const uint2 d = *(const uint2*)(t1b + (size_t)c * NH + lane * 4);
    a0 += v * bf2f((unsigned short)(d.x & 0xffffu));
    a1 += v * bf2f((unsigned short)(d.x >> 16));
    a2 += v * bf2f((unsigned short)(d.y & 0xffffu));
    a3 += v * bf2f((unsigned short)(d.y >> 16));
  }
  const int col = lane * 4;
  a0 = fmaxf(a0 + b1[col + 0], 0.f);
  a1 = fmaxf(a1 + b1[col + 1], 0.f);
  a2 = fmaxf(a2 + b1[col + 2], 0.f);
  a3 = fmaxf(a3 + b1[col + 3], 0.f);
  unsigned lo = (unsigned)f2bf(a0) | ((unsigned)f2bf(a1) << 16);
  unsigned hi = (unsigned)f2bf(a2) | ((unsigned)f2bf(a3) << 16);
  *(uint2*)(hb + (size_t)r * NH + col) = make_uint2(lo, hi);
}

// ---------------------------------------------------------------------------
// GEMM2: t2 = h @ W2 (bf16 in/out). A-frags direct from global (h is bf16),
// W2^T staged once in LDS. Block 256 thr = 4 waves, each 64 rows x 64 cols.
// ---------------------------------------------------------------------------
__global__ __launch_bounds__(256) void gemm2_mfma(const unsigned short* __restrict__ hb,
                                                  const float* __restrict__ W2,
                                                  unsigned short* __restrict__ t2b) {
  constexpr int LDB = 264;  // 256 + 8 pad
  __shared__ unsigned short Bs[64 * LDB];
  const int tid = threadIdx.x;
#pragma unroll
  for (int i = 0; i < 16; i++) {
    int it = tid + 256 * i;      // 0..4095
    int n = it & 63;
    int k4 = (it >> 6) * 4;      // 0..252
    float v0 = W2[(size_t)(k4 + 0) * NC + n];
    float v1 = W2[(size_t)(k4 + 1) * NC + n];
    float v2 = W2[(size_t)(k4 + 2) * NC + n];
    float v3 = W2[(size_t)(k4 + 3) * NC + n];
    unsigned lo = (unsigned)f2bf(v0) | ((unsigned)f2bf(v1) << 16);
    unsigned hi = (unsigned)f2bf(v2) | ((unsigned)f2bf(v3) << 16);
    *(uint2*)&Bs[n * LDB + k4] = make_uint2(lo, hi);
  }
  __syncthreads();
  const int w = tid >> 6, lane = tid & 63;
  const int quad = lane >> 4, l16 = lane & 15;
  const int m0 = blockIdx.x * 256 + w * 64;
  f32x4 acc[4][4] = {};
  const unsigned short* ap[4];
#pragma unroll
  for (int mt = 0; mt < 4; mt++) {
    int r = m0 + mt * 16 + l16; if (r > NN - 1) r = NN - 1;
    ap[mt] = hb + (size_t)r * NH + quad * 8;
  }
  for (int ks = 0; ks < 8; ks++) {
    bf16x8 a[4], b[4];
#pragma unroll
    for (int mt = 0; mt < 4; mt++) {
      const uint4 q = *(const uint4*)(ap[mt] + ks * 32);
      a[mt] = __builtin_bit_cast(bf16x8, q);
    }
#pragma unroll
    for (int nt = 0; nt < 4; nt++) {
      const uint4 q = *(const uint4*)&Bs[(nt * 16 + l16) * LDB + ks * 32 + quad * 8];
      b[nt] = __builtin_bit_cast(bf16x8, q);
    }
#pragma unroll
    for (int mt = 0; mt < 4; mt++)
#pragma unroll
      for (int nt = 0; nt < 4; nt++)
        acc[mt][nt] = __builtin_amdgcn_mfma_f32_16x16x32_bf16(a[mt], b[nt], acc[mt][nt], 0, 0, 0);
  }
#pragma unroll
  for (int mt = 0; mt < 4; mt++) {
#pragma unroll
    for (int reg = 0; reg < 4; reg++) {
      int row = m0 + mt * 16 + quad * 4 + reg;
      if (row < NN) {
#pragma unroll
        for (int nt = 0; nt < 4; nt++) {
          int col = nt * 16 + l16;
          t2b[(size_t)row * NC + col] = f2bf(acc[mt][nt][reg]);
        }
      }
    }
  }
}

// ---------------------------------------------------------------------------
// spmm2 + b2 + log_softmax + fc3 fused. One wave per row; lane = class idx.
// ---------------------------------------------------------------------------
__global__ __launch_bounds__(256) void spmm2_fused(const unsigned short* __restrict__ t2b,
                                                   const float* __restrict__ val_s,
                                                   const int* __restrict__ col_s,
                                                   const int* __restrict__ row_ptr,
                                                   const float* __restrict__ b2,
                                                   const float* __restrict__ W3,
                                                   const float* __restrict__ b3,
                                                   float* __restrict__ out0,
                                                   float* __restrict__ out1) {
  __shared__ float W3s[NC * NP];
  __shared__ float rz[4][NC];
  for (int it = threadIdx.x; it < NC * NP / 4; it += 256)
    ((float4*)W3s)[it] = ((const float4*)W3)[it];
  const int w = threadIdx.x >> 6, lane = threadIdx.x & 63;
  const int r = blockIdx.x * 4 + w;
  int s = row_ptr[r], e = row_ptr[r + 1];
  s = __builtin_amdgcn_readfirstlane(s);
  e = __builtin_amdgcn_readfirstlane(e);
  float acc = 0.f;
  for (int i = s; i < e; i++)
    acc += val_s[i] * bf2f(t2b[(size_t)col_s[i] * NC + lane]);
  const float z = acc + b2[lane];
  // log_softmax over the 64 lanes
  float m = z;
#pragma unroll
  for (int off = 32; off > 0; off >>= 1) m = fmaxf(m, __shfl_xor(m, off, 64));
  const float ex = expf(z - m);
  float sum = ex;
#pragma unroll
  for (int off = 32; off > 0; off >>= 1) sum += __shfl_xor(sum, off, 64);
  out0[(size_t)r * NC + lane] = z - m - logf(sum);
  rz[w][lane] = fmaxf(z, 0.f);
  __syncthreads();  // W3s ready + rz ready (each wave executes exactly once)
  float o0 = b3[lane], o1 = b3[64 + lane];
#pragma unroll 8
  for (int k = 0; k < NC; k++) {
    const float rk = rz[w][k];
    o0 += rk * W3s[k * NP + lane];
    o1 += rk * W3s[k * NP + 64 + lane];
  }
  out1[(size_t)r * NP + lane] = o0;
  out1[(size_t)r * NP + 64 + lane] = o1;
}

// ---------------------------------------------------------------------------
extern "C" void kernel_launch(void* const* d_in, const int* in_sizes, int n_in,
                              void* d_out, int out_size, void* d_ws, size_t ws_size,
                              hipStream_t stream) {
  const float* x    = (const float*)d_in[0];
  const float* vals = (const float*)d_in[1];
  const float* W1   = (const float*)d_in[2];
  const float* b1   = (const float*)d_in[3];
  const float* W2   = (const float*)d_in[4];
  const float* b2   = (const float*)d_in[5];
  const float* W3   = (const float*)d_in[6];
  const float* b3   = (const float*)d_in[7];
  const int* rows   = (const int*)d_in[8];
  const int* cols   = (const int*)d_in[9];

  char* ws = (char*)d_ws;
  // workspace layout (all offsets 256B-aligned), total ~141.6 MB
  unsigned short* t1b = (unsigned short*)(ws + 0);           // N*NH bf16 = 51.2 MB
  unsigned short* hb  = (unsigned short*)(ws + 51200000);    // N*NH bf16 = 51.2 MB
  unsigned short* t2b = (unsigned short*)(ws + 102400000);   // N*NC bf16 = 12.8 MB
  float* val_s        = (float*)(ws + 115200000);            // E f32 = 12.8 MB
  int*   col_s        = (int*)(ws + 128000000);              // E i32 = 12.8 MB
  int*   row_ptr      = (int*)(ws + 140800000);              // (N+1) i32
  int*   cursor       = (int*)(ws + 141201152);              // N i32
  int*   bsums        = (int*)(ws + 141601280);              // 98 i32
  int*   offs         = (int*)(ws + 141601792);              // 98 i32

  float* out0 = (float*)d_out;            // [N, 64] log_softmax(z)
  float* out1 = out0 + (size_t)NN * NC;   // [N, 128] fc3 output

  const int SCAN_BLKS = (NN + 1023) / 1024;  // 98

  // CSR build
  hipMemsetAsync(cursor, 0, (size_t)NN * sizeof(int), stream);  // cursor doubles as cnt
  hist_k<<<2048, 256, 0, stream>>>(rows, cursor);
  scanA_k<<<SCAN_BLKS, 256, 0, stream>>>(cursor, row_ptr, bsums);
  scanB_k<<<1, 128, 0, stream>>>(bsums, offs, SCAN_BLKS);
  scanC_k<<<SCAN_BLKS, 256, 0, stream>>>(row_ptr, cursor, offs);
  scatter_k<<<2048, 256, 0, stream>>>(rows, cols, vals, cursor, col_s, val_s);

  // pipeline
  gemm1_mfma<<<dim3((NN + 127) / 128, 2), 256, 0, stream>>>(x, W1, t1b);
  spmm1_relu<<<NN / 4, 256, 0, stream>>>(t1b, val_s, col_s, row_ptr, b1, hb);
  gemm2_mfma<<<(NN + 255) / 256, 256, 0, stream>>>(hb, W2, t2b);
  spmm2_fused<<<NN / 4, 256, 0, stream>>>(t2b, val_s, col_s, row_ptr, b2, W3, b3, out0, out1);
}

// Round 2
// 1281.870 us; speedup vs baseline: 1.1586x; 1.1586x over previous
//
#include <hip/hip_runtime.h>

// Problem constants (fixed by the reference)
static constexpr int NN = 100000;   // nodes
static constexpr int NE = 3200000;  // edges
static constexpr int KF = 512;      // NFEAT
static constexpr int NH = 256;      // NHID
static constexpr int NC = 64;       // NCLASS
static constexpr int NP = 128;      // PROJ

typedef __attribute__((ext_vector_type(4))) float f32x4;
typedef __attribute__((ext_vector_type(8))) __bf16 bf16x8;

__device__ __forceinline__ unsigned short f2bf(float f) {
  unsigned u = __builtin_bit_cast(unsigned, f);
  u += 0x7fffu + ((u >> 16) & 1u);   // RTNE
  return (unsigned short)(u >> 16);
}
__device__ __forceinline__ float bf2f(unsigned short h) {
  return __builtin_bit_cast(float, (unsigned)h << 16);
}

// ---------------------------------------------------------------------------
// CSR build: histogram -> 3-pass exclusive scan -> scatter (col,val) by row
// ---------------------------------------------------------------------------
__global__ void hist_k(const int* __restrict__ rows, int* __restrict__ cnt) {
  int stride = gridDim.x * blockDim.x;
  for (int e = blockIdx.x * blockDim.x + threadIdx.x; e < NE; e += stride)
    atomicAdd(&cnt[rows[e]], 1);
}

// 1024 elements per block, 4 per thread
__global__ __launch_bounds__(256) void scanA_k(const int* __restrict__ cnt,
                                               int* __restrict__ partial,
                                               int* __restrict__ bsums) {
  __shared__ int ts[256];
  const int t = threadIdx.x;
  const int base = blockIdx.x * 1024 + t * 4;
  int v[4]; int s = 0;
#pragma unroll
  for (int j = 0; j < 4; j++) { v[j] = (base + j < NN) ? cnt[base + j] : 0; s += v[j]; }
  ts[t] = s; __syncthreads();
  for (int off = 1; off < 256; off <<= 1) {
    int x2 = (t >= off) ? ts[t - off] : 0;
    __syncthreads();
    ts[t] += x2;
    __syncthreads();
  }
  int excl = ts[t] - s;
#pragma unroll
  for (int j = 0; j < 4; j++) {
    if (base + j < NN) partial[base + j] = excl;
    excl += v[j];
  }
  if (t == 255) bsums[blockIdx.x] = ts[255];
}

__global__ __launch_bounds__(128) void scanB_k(const int* __restrict__ bsums,
                                               int* __restrict__ offs, int nb) {
  __shared__ int ts[128];
  const int t = threadIdx.x;
  int v = (t < nb) ? bsums[t] : 0;
  ts[t] = v; __syncthreads();
  for (int off = 1; off < 128; off <<= 1) {
    int x2 = (t >= off) ? ts[t - off] : 0;
    __syncthreads();
    ts[t] += x2;
    __syncthreads();
  }
  if (t < nb) offs[t] = ts[t] - v;
}

__global__ __launch_bounds__(256) void scanC_k(int* __restrict__ row_ptr,
                                               int* __restrict__ cursor,
                                               const int* __restrict__ offs) {
  const int t = threadIdx.x;
  const int base = blockIdx.x * 1024 + t * 4;
  const int off = offs[blockIdx.x];
#pragma unroll
  for (int j = 0; j < 4; j++) {
    if (base + j < NN) {
      int vv = row_ptr[base + j] + off;
      row_ptr[base + j] = vv;
      cursor[base + j] = vv;
    }
  }
  if (blockIdx.x == 0 && t == 0) row_ptr[NN] = NE;
}

// packs (col, val) into one 8-byte record -> single random store per edge
__global__ void scatter_k(const int* __restrict__ rows, const int* __restrict__ cols,
                          const float* __restrict__ vals, int* __restrict__ cur,
                          uint2* __restrict__ edge_s) {
  int stride = gridDim.x * blockDim.x;
  for (int e = blockIdx.x * blockDim.x + threadIdx.x; e < NE; e += stride) {
    int pos = atomicAdd(&cur[rows[e]], 1);
    edge_s[pos] = make_uint2((unsigned)cols[e], __builtin_bit_cast(unsigned, vals[e]));
  }
}

// ---------------------------------------------------------------------------
// GEMM1: t1 = x @ W1  (fp32 in, bf16 out), MFMA 16x16x32_bf16
// Block: 256 thr = 4 waves (2m x 2n), tile 128x128, BK=64, K=512
// ---------------------------------------------------------------------------
__global__ __launch_bounds__(256) void gemm1_mfma(const float* __restrict__ x,
                                                  const float* __restrict__ W1,
                                                  unsigned short* __restrict__ t1b) {
  constexpr int LDA = 72;  // 64 + 8 pad (16B-aligned rows, 2-way bank alias = free)
  __shared__ unsigned short As[128 * LDA];
  __shared__ unsigned short Bs[128 * LDA];
  const int tid = threadIdx.x;
  const int m0 = blockIdx.x * 128;
  const int n0 = blockIdx.y * 128;
  const int w = tid >> 6, lane = tid & 63;
  const int wm = w & 1, wn = w >> 1;
  const int quad = lane >> 4, l16 = lane & 15;

  f32x4 acc[4][4] = {};

  for (int ks = 0; ks < 8; ks++) {
    __syncthreads();
    // stage A tile (128 rows x 64 k), fp32 -> bf16
#pragma unroll
    for (int i = 0; i < 8; i++) {
      int it = tid + 256 * i;       // 0..2047
      int row = it >> 4;            // 0..127
      int k4 = (it & 15) * 4;       // 0..60
      int gr = m0 + row; if (gr > NN - 1) gr = NN - 1;
      const float4 v = *(const float4*)(x + (size_t)gr * KF + ks * 64 + k4);
      unsigned lo = (unsigned)f2bf(v.x) | ((unsigned)f2bf(v.y) << 16);
      unsigned hi = (unsigned)f2bf(v.z) | ((unsigned)f2bf(v.w) << 16);
      *(uint2*)&As[row * LDA + k4] = make_uint2(lo, hi);
    }
    // stage B tile transposed: Bs[n][k]
#pragma unroll
    for (int i = 0; i < 8; i++) {
      int it = tid + 256 * i;       // 0..2047
      int n = it & 127;
      int k4 = (it >> 7) * 4;       // 0..60
      int gk = ks * 64 + k4;
      float v0 = W1[(size_t)(gk + 0) * NH + n0 + n];
      float v1 = W1[(size_t)(gk + 1) * NH + n0 + n];
      float v2 = W1[(size_t)(gk + 2) * NH + n0 + n];
      float v3 = W1[(size_t)(gk + 3) * NH + n0 + n];
      unsigned lo = (unsigned)f2bf(v0) | ((unsigned)f2bf(v1) << 16);
      unsigned hi = (unsigned)f2bf(v2) | ((unsigned)f2bf(v3) << 16);
      *(uint2*)&Bs[n * LDA + k4] = make_uint2(lo, hi);
    }
    __syncthreads();
#pragma unroll
    for (int kk = 0; kk < 2; kk++) {
      bf16x8 a[4], b[4];
#pragma unroll
      for (int mt = 0; mt < 4; mt++) {
        const uint4 q = *(const uint4*)&As[(wm * 64 + mt * 16 + l16) * LDA + kk * 32 + quad * 8];
        a[mt] = __builtin_bit_cast(bf16x8, q);
      }
#pragma unroll
      for (int nt = 0; nt < 4; nt++) {
        const uint4 q = *(const uint4*)&Bs[(wn * 64 + nt * 16 + l16) * LDA + kk * 32 + quad * 8];
        b[nt] = __builtin_bit_cast(bf16x8, q);
      }
#pragma unroll
      for (int mt = 0; mt < 4; mt++)
#pragma unroll
        for (int nt = 0; nt < 4; nt++)
          acc[mt][nt] = __builtin_amdgcn_mfma_f32_16x16x32_bf16(a[mt], b[nt], acc[mt][nt], 0, 0, 0);
    }
  }
  // epilogue: C/D layout col=lane&15, row=quad*4+reg
#pragma unroll
  for (int mt = 0; mt < 4; mt++) {
#pragma unroll
    for (int reg = 0; reg < 4; reg++) {
      int row = m0 + wm * 64 + mt * 16 + quad * 4 + reg;
      if (row < NN) {
#pragma unroll
        for (int nt = 0; nt < 4; nt++) {
          int col = n0 + wn * 64 + nt * 16 + l16;
          t1b[(size_t)row * NH + col] = f2bf(acc[mt][nt][reg]);
        }
      }
    }
  }
}

// ---------------------------------------------------------------------------
// spmm1: h = relu(spmm(t1) + b1), CSR, one wave per row, 4 cols/lane.
// Edge loop unrolled x8: 8 edge records then 8 independent gathers in flight.
// Tail: clamp index to e-1, zero the weight (no serial remainder).
// ---------------------------------------------------------------------------
__global__ __launch_bounds__(256) void spmm1_relu(const unsigned short* __restrict__ t1b,
                                                  const uint2* __restrict__ edge,
                                                  const int* __restrict__ row_ptr,
                                                  const float* __restrict__ b1,
                                                  unsigned short* __restrict__ hb) {
  const int w = threadIdx.x >> 6, lane = threadIdx.x & 63;
  const int r = blockIdx.x * 4 + w;
  int s = row_ptr[r], e = row_ptr[r + 1];
  s = __builtin_amdgcn_readfirstlane(s);
  e = __builtin_amdgcn_readfirstlane(e);
  float a0 = 0.f, a1 = 0.f, a2 = 0.f, a3 = 0.f;
  for (int i = s; i < e; i += 8) {
    uint2 ed[8];
#pragma unroll
    for (int j = 0; j < 8; j++) {
      const int idx = i + j;
      uint2 t = edge[idx < e ? idx : (e - 1)];
      if (idx >= e) t.y = 0u;          // zero weight for tail slots
      ed[j] = t;
    }
    uint2 d[8];
#pragma unroll
    for (int j = 0; j < 8; j++)
      d[j] = *(const uint2*)(t1b + (size_t)ed[j].x * NH + lane * 4);
#pragma unroll
    for (int j = 0; j < 8; j++) {
      const float v = __builtin_bit_cast(float, ed[j].y);
      a0 += v * bf2f((unsigned short)(d[j].x & 0xffffu));
      a1 += v * bf2f((unsigned short)(d[j].x >> 16));
      a2 += v * bf2f((unsigned short)(d[j].y & 0xffffu));
      a3 += v * bf2f((unsigned short)(d[j].y >> 16));
    }
  }
  const int col = lane * 4;
  a0 = fmaxf(a0 + b1[col + 0], 0.f);
  a1 = fmaxf(a1 + b1[col + 1], 0.f);
  a2 = fmaxf(a2 + b1[col + 2], 0.f);
  a3 = fmaxf(a3 + b1[col + 3], 0.f);
  unsigned lo = (unsigned)f2bf(a0) | ((unsigned)f2bf(a1) << 16);
  unsigned hi = (unsigned)f2bf(a2) | ((unsigned)f2bf(a3) << 16);
  *(uint2*)(hb + (size_t)r * NH + col) = make_uint2(lo, hi);
}

// ---------------------------------------------------------------------------
// GEMM2: t2 = h @ W2 (bf16 in/out). A-frags direct from global (h is bf16),
// W2^T staged once in LDS. Block 256 thr = 4 waves, each 64 rows x 64 cols.
// ---------------------------------------------------------------------------
__global__ __launch_bounds__(256) void gemm2_mfma(const unsigned short* __restrict__ hb,
                                                  const float* __restrict__ W2,
                                                  unsigned short* __restrict__ t2b) {
  constexpr int LDB = 264;  // 256 + 8 pad
  __shared__ unsigned short Bs[64 * LDB];
  const int tid = threadIdx.x;
#pragma unroll
  for (int i = 0; i < 16; i++) {
    int it = tid + 256 * i;      // 0..4095
    int n = it & 63;
    int k4 = (it >> 6) * 4;      // 0..252
    float v0 = W2[(size_t)(k4 + 0) * NC + n];
    float v1 = W2[(size_t)(k4 + 1) * NC + n];
    float v2 = W2[(size_t)(k4 + 2) * NC + n];
    float v3 = W2[(size_t)(k4 + 3) * NC + n];
    unsigned lo = (unsigned)f2bf(v0) | ((unsigned)f2bf(v1) << 16);
    unsigned hi = (unsigned)f2bf(v2) | ((unsigned)f2bf(v3) << 16);
    *(uint2*)&Bs[n * LDB + k4] = make_uint2(lo, hi);
  }
  __syncthreads();
  const int w = tid >> 6, lane = tid & 63;
  const int quad = lane >> 4, l16 = lane & 15;
  const int m0 = blockIdx.x * 256 + w * 64;
  f32x4 acc[4][4] = {};
  const unsigned short* ap[4];
#pragma unroll
  for (int mt = 0; mt < 4; mt++) {
    int r = m0 + mt * 16 + l16; if (r > NN - 1) r = NN - 1;
    ap[mt] = hb + (size_t)r * NH + quad * 8;
  }
  for (int ks = 0; ks < 8; ks++) {
    bf16x8 a[4], b[4];
#pragma unroll
    for (int mt = 0; mt < 4; mt++) {
      const uint4 q = *(const uint4*)(ap[mt] + ks * 32);
      a[mt] = __builtin_bit_cast(bf16x8, q);
    }
#pragma unroll
    for (int nt = 0; nt < 4; nt++) {
      const uint4 q = *(const uint4*)&Bs[(nt * 16 + l16) * LDB + ks * 32 + quad * 8];
      b[nt] = __builtin_bit_cast(bf16x8, q);
    }
#pragma unroll
    for (int mt = 0; mt < 4; mt++)
#pragma unroll
      for (int nt = 0; nt < 4; nt++)
        acc[mt][nt] = __builtin_amdgcn_mfma_f32_16x16x32_bf16(a[mt], b[nt], acc[mt][nt], 0, 0, 0);
  }
#pragma unroll
  for (int mt = 0; mt < 4; mt++) {
#pragma unroll
    for (int reg = 0; reg < 4; reg++) {
      int row = m0 + mt * 16 + quad * 4 + reg;
      if (row < NN) {
#pragma unroll
        for (int nt = 0; nt < 4; nt++) {
          int col = nt * 16 + l16;
          t2b[(size_t)row * NC + col] = f2bf(acc[mt][nt][reg]);
        }
      }
    }
  }
}

// ---------------------------------------------------------------------------
// spmm2 + b2 + log_softmax + fc3 fused. One wave per row; lane = class idx.
// Edge loop unrolled x8 (same MLP trick as spmm1).
// ---------------------------------------------------------------------------
__global__ __launch_bounds__(256) void spmm2_fused(const unsigned short* __restrict__ t2b,
                                                   const uint2* __restrict__ edge,
                                                   const int* __restrict__ row_ptr,
                                                   const float* __restrict__ b2,
                                                   const float* __restrict__ W3,
                                                   const float* __restrict__ b3,
                                                   float* __restrict__ out0,
                                                   float* __restrict__ out1) {
  __shared__ float W3s[NC * NP];
  __shared__ float rz[4][NC];
  for (int it = threadIdx.x; it < NC * NP / 4; it += 256)
    ((float4*)W3s)[it] = ((const float4*)W3)[it];
  const int w = threadIdx.x >> 6, lane = threadIdx.x & 63;
  const int r = blockIdx.x * 4 + w;
  int s = row_ptr[r], e = row_ptr[r + 1];
  s = __builtin_amdgcn_readfirstlane(s);
  e = __builtin_amdgcn_readfirstlane(e);
  float acc = 0.f;
  for (int i = s; i < e; i += 8) {
    uint2 ed[8];
#pragma unroll
    for (int j = 0; j < 8; j++) {
      const int idx = i + j;
      uint2 t = edge[idx < e ? idx : (e - 1)];
      if (idx >= e) t.y = 0u;
      ed[j] = t;
    }
    float g[8];
#pragma unroll
    for (int j = 0; j < 8; j++)
      g[j] = bf2f(t2b[(size_t)ed[j].x * NC + lane]);
#pragma unroll
    for (int j = 0; j < 8; j++)
      acc += __builtin_bit_cast(float, ed[j].y) * g[j];
  }
  const float z = acc + b2[lane];
  // log_softmax over the 64 lanes
  float m = z;
#pragma unroll
  for (int off = 32; off > 0; off >>= 1) m = fmaxf(m, __shfl_xor(m, off, 64));
  const float ex = expf(z - m);
  float sum = ex;
#pragma unroll
  for (int off = 32; off > 0; off >>= 1) sum += __shfl_xor(sum, off, 64);
  out0[(size_t)r * NC + lane] = z - m - logf(sum);
  rz[w][lane] = fmaxf(z, 0.f);
  __syncthreads();  // W3s ready + rz ready (each wave executes exactly once)
  float o0 = b3[lane], o1 = b3[64 + lane];
#pragma unroll 8
  for (int k = 0; k < NC; k++) {
    const float rk = rz[w][k];
    o0 += rk * W3s[k * NP + lane];
    o1 += rk * W3s[k * NP + 64 + lane];
  }
  out1[(size_t)r * NP + lane] = o0;
  out1[(size_t)r * NP + 64 + lane] = o1;
}

// ---------------------------------------------------------------------------
extern "C" void kernel_launch(void* const* d_in, const int* in_sizes, int n_in,
                              void* d_out, int out_size, void* d_ws, size_t ws_size,
                              hipStream_t stream) {
  const float* x    = (const float*)d_in[0];
  const float* vals = (const float*)d_in[1];
  const float* W1   = (const float*)d_in[2];
  const float* b1   = (const float*)d_in[3];
  const float* W2   = (const float*)d_in[4];
  const float* b2   = (const float*)d_in[5];
  const float* W3   = (const float*)d_in[6];
  const float* b3   = (const float*)d_in[7];
  const int* rows   = (const int*)d_in[8];
  const int* cols   = (const int*)d_in[9];

  char* ws = (char*)d_ws;
  // workspace layout (all offsets 256B-aligned), total ~141.6 MB
  unsigned short* t1b = (unsigned short*)(ws + 0);           // N*NH bf16 = 51.2 MB
  unsigned short* hb  = (unsigned short*)(ws + 51200000);    // N*NH bf16 = 51.2 MB
  unsigned short* t2b = (unsigned short*)(ws + 102400000);   // N*NC bf16 = 12.8 MB
  uint2* edge_s       = (uint2*)(ws + 115200000);            // E x 8B = 25.6 MB
  int*   row_ptr      = (int*)(ws + 140800000);              // (N+1) i32
  int*   cursor       = (int*)(ws + 141201152);              // N i32
  int*   bsums        = (int*)(ws + 141601280);              // 98 i32
  int*   offs         = (int*)(ws + 141601792);              // 98 i32

  float* out0 = (float*)d_out;            // [N, 64] log_softmax(z)
  float* out1 = out0 + (size_t)NN * NC;   // [N, 128] fc3 output

  const int SCAN_BLKS = (NN + 1023) / 1024;  // 98

  // CSR build
  hipMemsetAsync(cursor, 0, (size_t)NN * sizeof(int), stream);  // cursor doubles as cnt
  hist_k<<<2048, 256, 0, stream>>>(rows, cursor);
  scanA_k<<<SCAN_BLKS, 256, 0, stream>>>(cursor, row_ptr, bsums);
  scanB_k<<<1, 128, 0, stream>>>(bsums, offs, SCAN_BLKS);
  scanC_k<<<SCAN_BLKS, 256, 0, stream>>>(row_ptr, cursor, offs);
  scatter_k<<<2048, 256, 0, stream>>>(rows, cols, vals, cursor, edge_s);

  // pipeline
  gemm1_mfma<<<dim3((NN + 127) / 128, 2), 256, 0, stream>>>(x, W1, t1b);
  spmm1_relu<<<NN / 4, 256, 0, stream>>>(t1b, edge_s, row_ptr, b1, hb);
  gemm2_mfma<<<(NN + 255) / 256, 256, 0, stream>>>(hb, W2, t2b);
  spmm2_fused<<<NN / 4, 256, 0, stream>>>(t2b, edge_s, row_ptr, b2, W3, b3, out0, out1);
}

// Round 3
// 1128.599 us; speedup vs baseline: 1.3160x; 1.1358x over previous
//
#include <hip/hip_runtime.h>

// Problem constants (fixed by the reference)
static constexpr int NN = 100000;   // nodes
static constexpr int NE = 3200000;  // edges
static constexpr int KF = 512;      // NFEAT
static constexpr int NH = 256;      // NHID
static constexpr int NC = 64;       // NCLASS
static constexpr int NP = 128;      // PROJ

static constexpr int NB = 782;      // ceil(NN/128) buckets of 128 rows
static constexpr int TILE = 16384;  // edges per workgroup in binning pass
static constexpr int NTILES = (NE + TILE - 1) / TILE;  // 196

typedef __attribute__((ext_vector_type(4))) float f32x4;
typedef __attribute__((ext_vector_type(8))) __bf16 bf16x8;

__device__ __forceinline__ unsigned short f2bf(float f) {
  unsigned u = __builtin_bit_cast(unsigned, f);
  u += 0x7fffu + ((u >> 16) & 1u);   // RTNE
  return (unsigned short)(u >> 16);
}
__device__ __forceinline__ float bf2f(unsigned short h) {
  return __builtin_bit_cast(float, (unsigned)h << 16);
}

// ---------------------------------------------------------------------------
// CSR build, two-phase multisplit:
//   bhist -> bscan -> phase1(bucket-bin, LDS-combined) -> rowhist -> scans ->
//   phase2 (bucket-local exact scatter)
// ---------------------------------------------------------------------------
__global__ __launch_bounds__(256) void bhist_k(const int* __restrict__ rows,
                                               int* __restrict__ bcnt) {
  __shared__ int cnt[NB];
  for (int i = threadIdx.x; i < NB; i += 256) cnt[i] = 0;
  __syncthreads();
  const int e0 = blockIdx.x * TILE;
  for (int i = threadIdx.x; i < TILE; i += 256) {
    int e = e0 + i;
    if (e < NE) atomicAdd(&cnt[rows[e] >> 7], 1);
  }
  __syncthreads();
  for (int i = threadIdx.x; i < NB; i += 256)
    if (cnt[i] > 0) atomicAdd(&bcnt[i], cnt[i]);
}

// single workgroup exclusive scan of bcnt[NB] -> bucket_ptr[NB+1], bcur[NB]
__global__ __launch_bounds__(256) void bscan_k(const int* __restrict__ bcnt,
                                               int* __restrict__ bucket_ptr,
                                               int* __restrict__ bcur) {
  __shared__ int ts[256];
  const int t = threadIdx.x;
  const int base = t * 4;
  int v[4]; int ssum = 0;
#pragma unroll
  for (int j = 0; j < 4; j++) { v[j] = (base + j < NB) ? bcnt[base + j] : 0; ssum += v[j]; }
  ts[t] = ssum; __syncthreads();
  for (int off = 1; off < 256; off <<= 1) {
    int x2 = (t >= off) ? ts[t - off] : 0;
    __syncthreads();
    ts[t] += x2;
    __syncthreads();
  }
  int excl = ts[t] - ssum;
#pragma unroll
  for (int j = 0; j < 4; j++) {
    if (base + j < NB) { bucket_ptr[base + j] = excl; bcur[base + j] = excl; }
    excl += v[j];
  }
  if (t == 255) bucket_ptr[NB] = NE;
}

// bin edges into bucket-contiguous stage[]; record = (row_local<<17 | col, val)
__global__ __launch_bounds__(256) void phase1_bin(const int* __restrict__ rows,
                                                  const int* __restrict__ cols,
                                                  const float* __restrict__ vals,
                                                  int* __restrict__ bcur,
                                                  uint2* __restrict__ stage) {
  __shared__ int cnt[NB];
  __shared__ int gpos[NB];
  const int t = threadIdx.x;
  const int e0 = blockIdx.x * TILE;
  for (int i = t; i < NB; i += 256) cnt[i] = 0;
  __syncthreads();
  // pass a: count per bucket within this tile
  for (int i = t; i < TILE; i += 256) {
    int e = e0 + i;
    if (e < NE) atomicAdd(&cnt[rows[e] >> 7], 1);
  }
  __syncthreads();
  // reserve contiguous global chunks per bucket
  for (int b = t; b < NB; b += 256) {
    int c = cnt[b];
    gpos[b] = (c > 0) ? atomicAdd(&bcur[b], c) : 0;
    cnt[b] = 0;
  }
  __syncthreads();
  // pass b: place records (chunk-contiguous -> L2 merges into full lines)
  for (int i = t; i < TILE; i += 256) {
    int e = e0 + i;
    if (e < NE) {
      int r = rows[e];
      int b = r >> 7;
      int rank = atomicAdd(&cnt[b], 1);
      unsigned w0 = ((unsigned)(r & 127) << 17) | (unsigned)cols[e];
      stage[gpos[b] + rank] = make_uint2(w0, __builtin_bit_cast(unsigned, vals[e]));
    }
  }
}

// per-row histogram from bucket-grouped stage (LDS counters, no random atomics)
__global__ __launch_bounds__(256) void rowhist_k(const uint2* __restrict__ stage,
                                                 const int* __restrict__ bucket_ptr,
                                                 int* __restrict__ row_cnt) {
  __shared__ int cnt[128];
  const int b = blockIdx.x;
  const int t = threadIdx.x;
  if (t < 128) cnt[t] = 0;
  __syncthreads();
  const int s = bucket_ptr[b], e = bucket_ptr[b + 1];
  for (int i = s + t; i < e; i += 256)
    atomicAdd(&cnt[stage[i].x >> 17], 1);
  __syncthreads();
  int row = b * 128 + t;
  if (t < 128 && row < NN) row_cnt[row] = cnt[t];
}

// 1024 elements per block, 4 per thread
__global__ __launch_bounds__(256) void scanA_k(const int* __restrict__ cnt,
                                               int* __restrict__ partial,
                                               int* __restrict__ bsums) {
  __shared__ int ts[256];
  const int t = threadIdx.x;
  const int base = blockIdx.x * 1024 + t * 4;
  int v[4]; int s = 0;
#pragma unroll
  for (int j = 0; j < 4; j++) { v[j] = (base + j < NN) ? cnt[base + j] : 0; s += v[j]; }
  ts[t] = s; __syncthreads();
  for (int off = 1; off < 256; off <<= 1) {
    int x2 = (t >= off) ? ts[t - off] : 0;
    __syncthreads();
    ts[t] += x2;
    __syncthreads();
  }
  int excl = ts[t] - s;
#pragma unroll
  for (int j = 0; j < 4; j++) {
    if (base + j < NN) partial[base + j] = excl;
    excl += v[j];
  }
  if (t == 255) bsums[blockIdx.x] = ts[255];
}

__global__ __launch_bounds__(128) void scanB_k(const int* __restrict__ bsums,
                                               int* __restrict__ offs, int nb) {
  __shared__ int ts[128];
  const int t = threadIdx.x;
  int v = (t < nb) ? bsums[t] : 0;
  ts[t] = v; __syncthreads();
  for (int off = 1; off < 128; off <<= 1) {
    int x2 = (t >= off) ? ts[t - off] : 0;
    __syncthreads();
    ts[t] += x2;
    __syncthreads();
  }
  if (t < nb) offs[t] = ts[t] - v;
}

__global__ __launch_bounds__(256) void scanC_k(int* __restrict__ row_ptr,
                                               int* __restrict__ cursor,
                                               const int* __restrict__ offs) {
  const int t = threadIdx.x;
  const int base = blockIdx.x * 1024 + t * 4;
  const int off = offs[blockIdx.x];
#pragma unroll
  for (int j = 0; j < 4; j++) {
    if (base + j < NN) {
      int vv = row_ptr[base + j] + off;
      row_ptr[base + j] = vv;
      cursor[base + j] = vv;
    }
  }
  if (blockIdx.x == 0 && t == 0) row_ptr[NN] = NE;
}

// exact scatter within one bucket: 32 KB L2-resident write window -> full lines
__global__ __launch_bounds__(256) void phase2_k(const uint2* __restrict__ stage,
                                                const int* __restrict__ bucket_ptr,
                                                int* __restrict__ cursor,
                                                uint2* __restrict__ edge_s) {
  const int b = blockIdx.x;
  const int base = b * 128;
  const int s = bucket_ptr[b], e = bucket_ptr[b + 1];
  for (int i0 = s + threadIdx.x * 4; i0 < e; i0 += 1024) {
#pragma unroll
    for (int j = 0; j < 4; j++) {
      int idx = i0 + j;
      if (idx < e) {
        uint2 rec = stage[idx];
        int row = base + (int)(rec.x >> 17);
        int pos = atomicAdd(&cursor[row], 1);
        edge_s[pos] = make_uint2(rec.x & 0x1FFFFu, rec.y);
      }
    }
  }
}

// ---------------------------------------------------------------------------
// GEMM1: t1 = x @ W1  (fp32 in, bf16 out), MFMA 16x16x32_bf16
// ---------------------------------------------------------------------------
__global__ __launch_bounds__(256) void gemm1_mfma(const float* __restrict__ x,
                                                  const float* __restrict__ W1,
                                                  unsigned short* __restrict__ t1b) {
  constexpr int LDA = 72;  // 64 + 8 pad
  __shared__ unsigned short As[128 * LDA];
  __shared__ unsigned short Bs[128 * LDA];
  const int tid = threadIdx.x;
  const int m0 = blockIdx.x * 128;
  const int n0 = blockIdx.y * 128;
  const int w = tid >> 6, lane = tid & 63;
  const int wm = w & 1, wn = w >> 1;
  const int quad = lane >> 4, l16 = lane & 15;

  f32x4 acc[4][4] = {};

  for (int ks = 0; ks < 8; ks++) {
    __syncthreads();
#pragma unroll
    for (int i = 0; i < 8; i++) {
      int it = tid + 256 * i;
      int row = it >> 4;
      int k4 = (it & 15) * 4;
      int gr = m0 + row; if (gr > NN - 1) gr = NN - 1;
      const float4 v = *(const float4*)(x + (size_t)gr * KF + ks * 64 + k4);
      unsigned lo = (unsigned)f2bf(v.x) | ((unsigned)f2bf(v.y) << 16);
      unsigned hi = (unsigned)f2bf(v.z) | ((unsigned)f2bf(v.w) << 16);
      *(uint2*)&As[row * LDA + k4] = make_uint2(lo, hi);
    }
#pragma unroll
    for (int i = 0; i < 8; i++) {
      int it = tid + 256 * i;
      int n = it & 127;
      int k4 = (it >> 7) * 4;
      int gk = ks * 64 + k4;
      float v0 = W1[(size_t)(gk + 0) * NH + n0 + n];
      float v1 = W1[(size_t)(gk + 1) * NH + n0 + n];
      float v2 = W1[(size_t)(gk + 2) * NH + n0 + n];
      float v3 = W1[(size_t)(gk + 3) * NH + n0 + n];
      unsigned lo = (unsigned)f2bf(v0) | ((unsigned)f2bf(v1) << 16);
      unsigned hi = (unsigned)f2bf(v2) | ((unsigned)f2bf(v3) << 16);
      *(uint2*)&Bs[n * LDA + k4] = make_uint2(lo, hi);
    }
    __syncthreads();
#pragma unroll
    for (int kk = 0; kk < 2; kk++) {
      bf16x8 a[4], b[4];
#pragma unroll
      for (int mt = 0; mt < 4; mt++) {
        const uint4 q = *(const uint4*)&As[(wm * 64 + mt * 16 + l16) * LDA + kk * 32 + quad * 8];
        a[mt] = __builtin_bit_cast(bf16x8, q);
      }
#pragma unroll
      for (int nt = 0; nt < 4; nt++) {
        const uint4 q = *(const uint4*)&Bs[(wn * 64 + nt * 16 + l16) * LDA + kk * 32 + quad * 8];
        b[nt] = __builtin_bit_cast(bf16x8, q);
      }
#pragma unroll
      for (int mt = 0; mt < 4; mt++)
#pragma unroll
        for (int nt = 0; nt < 4; nt++)
          acc[mt][nt] = __builtin_amdgcn_mfma_f32_16x16x32_bf16(a[mt], b[nt], acc[mt][nt], 0, 0, 0);
    }
  }
#pragma unroll
  for (int mt = 0; mt < 4; mt++) {
#pragma unroll
    for (int reg = 0; reg < 4; reg++) {
      int row = m0 + wm * 64 + mt * 16 + quad * 4 + reg;
      if (row < NN) {
#pragma unroll
        for (int nt = 0; nt < 4; nt++) {
          int col = n0 + wn * 64 + nt * 16 + l16;
          t1b[(size_t)row * NH + col] = f2bf(acc[mt][nt][reg]);
        }
      }
    }
  }
}

// ---------------------------------------------------------------------------
// spmm1: h = relu(spmm(t1) + b1), CSR, one wave per row, x8 unrolled gather
// ---------------------------------------------------------------------------
__global__ __launch_bounds__(256) void spmm1_relu(const unsigned short* __restrict__ t1b,
                                                  const uint2* __restrict__ edge,
                                                  const int* __restrict__ row_ptr,
                                                  const float* __restrict__ b1,
                                                  unsigned short* __restrict__ hb) {
  const int w = threadIdx.x >> 6, lane = threadIdx.x & 63;
  const int r = blockIdx.x * 4 + w;
  int s = row_ptr[r], e = row_ptr[r + 1];
  s = __builtin_amdgcn_readfirstlane(s);
  e = __builtin_amdgcn_readfirstlane(e);
  float a0 = 0.f, a1 = 0.f, a2 = 0.f, a3 = 0.f;
  for (int i = s; i < e; i += 8) {
    uint2 ed[8];
#pragma unroll
    for (int j = 0; j < 8; j++) {
      const int idx = i + j;
      uint2 t = edge[idx < e ? idx : (e - 1)];
      if (idx >= e) t.y = 0u;
      ed[j] = t;
    }
    uint2 d[8];
#pragma unroll
    for (int j = 0; j < 8; j++)
      d[j] = *(const uint2*)(t1b + (size_t)ed[j].x * NH + lane * 4);
#pragma unroll
    for (int j = 0; j < 8; j++) {
      const float v = __builtin_bit_cast(float, ed[j].y);
      a0 += v * bf2f((unsigned short)(d[j].x & 0xffffu));
      a1 += v * bf2f((unsigned short)(d[j].x >> 16));
      a2 += v * bf2f((unsigned short)(d[j].y & 0xffffu));
      a3 += v * bf2f((unsigned short)(d[j].y >> 16));
    }
  }
  const int col = lane * 4;
  a0 = fmaxf(a0 + b1[col + 0], 0.f);
  a1 = fmaxf(a1 + b1[col + 1], 0.f);
  a2 = fmaxf(a2 + b1[col + 2], 0.f);
  a3 = fmaxf(a3 + b1[col + 3], 0.f);
  unsigned lo = (unsigned)f2bf(a0) | ((unsigned)f2bf(a1) << 16);
  unsigned hi = (unsigned)f2bf(a2) | ((unsigned)f2bf(a3) << 16);
  *(uint2*)(hb + (size_t)r * NH + col) = make_uint2(lo, hi);
}

// ---------------------------------------------------------------------------
// GEMM2: t2 = h @ W2 (bf16 in/out)
// ---------------------------------------------------------------------------
__global__ __launch_bounds__(256) void gemm2_mfma(const unsigned short* __restrict__ hb,
                                                  const float* __restrict__ W2,
                                                  unsigned short* __restrict__ t2b) {
  constexpr int LDB = 264;  // 256 + 8 pad
  __shared__ unsigned short Bs[64 * LDB];
  const int tid = threadIdx.x;
#pragma unroll
  for (int i = 0; i < 16; i++) {
    int it = tid + 256 * i;
    int n = it & 63;
    int k4 = (it >> 6) * 4;
    float v0 = W2[(size_t)(k4 + 0) * NC + n];
    float v1 = W2[(size_t)(k4 + 1) * NC + n];
    float v2 = W2[(size_t)(k4 + 2) * NC + n];
    float v3 = W2[(size_t)(k4 + 3) * NC + n];
    unsigned lo = (unsigned)f2bf(v0) | ((unsigned)f2bf(v1) << 16);
    unsigned hi = (unsigned)f2bf(v2) | ((unsigned)f2bf(v3) << 16);
    *(uint2*)&Bs[n * LDB + k4] = make_uint2(lo, hi);
  }
  __syncthreads();
  const int w = tid >> 6, lane = tid & 63;
  const int quad = lane >> 4, l16 = lane & 15;
  const int m0 = blockIdx.x * 256 + w * 64;
  f32x4 acc[4][4] = {};
  const unsigned short* ap[4];
#pragma unroll
  for (int mt = 0; mt < 4; mt++) {
    int r = m0 + mt * 16 + l16; if (r > NN - 1) r = NN - 1;
    ap[mt] = hb + (size_t)r * NH + quad * 8;
  }
  for (int ks = 0; ks < 8; ks++) {
    bf16x8 a[4], b[4];
#pragma unroll
    for (int mt = 0; mt < 4; mt++) {
      const uint4 q = *(const uint4*)(ap[mt] + ks * 32);
      a[mt] = __builtin_bit_cast(bf16x8, q);
    }
#pragma unroll
    for (int nt = 0; nt < 4; nt++) {
      const uint4 q = *(const uint4*)&Bs[(nt * 16 + l16) * LDB + ks * 32 + quad * 8];
      b[nt] = __builtin_bit_cast(bf16x8, q);
    }
#pragma unroll
    for (int mt = 0; mt < 4; mt++)
#pragma unroll
      for (int nt = 0; nt < 4; nt++)
        acc[mt][nt] = __builtin_amdgcn_mfma_f32_16x16x32_bf16(a[mt], b[nt], acc[mt][nt], 0, 0, 0);
  }
#pragma unroll
  for (int mt = 0; mt < 4; mt++) {
#pragma unroll
    for (int reg = 0; reg < 4; reg++) {
      int row = m0 + mt * 16 + quad * 4 + reg;
      if (row < NN) {
#pragma unroll
        for (int nt = 0; nt < 4; nt++) {
          int col = nt * 16 + l16;
          t2b[(size_t)row * NC + col] = f2bf(acc[mt][nt][reg]);
        }
      }
    }
  }
}

// ---------------------------------------------------------------------------
// spmm2 + b2 + log_softmax + fc3 fused. One wave per row; lane = class idx.
// ---------------------------------------------------------------------------
__global__ __launch_bounds__(256) void spmm2_fused(const unsigned short* __restrict__ t2b,
                                                   const uint2* __restrict__ edge,
                                                   const int* __restrict__ row_ptr,
                                                   const float* __restrict__ b2,
                                                   const float* __restrict__ W3,
                                                   const float* __restrict__ b3,
                                                   float* __restrict__ out0,
                                                   float* __restrict__ out1) {
  __shared__ float W3s[NC * NP];
  __shared__ float rz[4][NC];
  for (int it = threadIdx.x; it < NC * NP / 4; it += 256)
    ((float4*)W3s)[it] = ((const float4*)W3)[it];
  const int w = threadIdx.x >> 6, lane = threadIdx.x & 63;
  const int r = blockIdx.x * 4 + w;
  int s = row_ptr[r], e = row_ptr[r + 1];
  s = __builtin_amdgcn_readfirstlane(s);
  e = __builtin_amdgcn_readfirstlane(e);
  float acc = 0.f;
  for (int i = s; i < e; i += 8) {
    uint2 ed[8];
#pragma unroll
    for (int j = 0; j < 8; j++) {
      const int idx = i + j;
      uint2 t = edge[idx < e ? idx : (e - 1)];
      if (idx >= e) t.y = 0u;
      ed[j] = t;
    }
    float g[8];
#pragma unroll
    for (int j = 0; j < 8; j++)
      g[j] = bf2f(t2b[(size_t)ed[j].x * NC + lane]);
#pragma unroll
    for (int j = 0; j < 8; j++)
      acc += __builtin_bit_cast(float, ed[j].y) * g[j];
  }
  const float z = acc + b2[lane];
  float m = z;
#pragma unroll
  for (int off = 32; off > 0; off >>= 1) m = fmaxf(m, __shfl_xor(m, off, 64));
  const float ex = expf(z - m);
  float sum = ex;
#pragma unroll
  for (int off = 32; off > 0; off >>= 1) sum += __shfl_xor(sum, off, 64);
  out0[(size_t)r * NC + lane] = z - m - logf(sum);
  rz[w][lane] = fmaxf(z, 0.f);
  __syncthreads();
  float o0 = b3[lane], o1 = b3[64 + lane];
#pragma unroll 8
  for (int k = 0; k < NC; k++) {
    const float rk = rz[w][k];
    o0 += rk * W3s[k * NP + lane];
    o1 += rk * W3s[k * NP + 64 + lane];
  }
  out1[(size_t)r * NP + lane] = o0;
  out1[(size_t)r * NP + 64 + lane] = o1;
}

// ---------------------------------------------------------------------------
extern "C" void kernel_launch(void* const* d_in, const int* in_sizes, int n_in,
                              void* d_out, int out_size, void* d_ws, size_t ws_size,
                              hipStream_t stream) {
  const float* x    = (const float*)d_in[0];
  const float* vals = (const float*)d_in[1];
  const float* W1   = (const float*)d_in[2];
  const float* b1   = (const float*)d_in[3];
  const float* W2   = (const float*)d_in[4];
  const float* b2   = (const float*)d_in[5];
  const float* W3   = (const float*)d_in[6];
  const float* b3   = (const float*)d_in[7];
  const int* rows   = (const int*)d_in[8];
  const int* cols   = (const int*)d_in[9];

  char* ws = (char*)d_ws;
  // workspace layout. stage aliases t1b: phase2 finishes before gemm1 writes t1b
  // (single stream => serialized).
  unsigned short* t1b = (unsigned short*)(ws + 0);           // N*NH bf16 = 51.2 MB
  uint2* stage        = (uint2*)(ws + 0);                    // E x 8B = 25.6 MB (alias)
  unsigned short* hb  = (unsigned short*)(ws + 51200000);    // 51.2 MB
  unsigned short* t2b = (unsigned short*)(ws + 102400000);   // 12.8 MB
  uint2* edge_s       = (uint2*)(ws + 115200000);            // 25.6 MB
  int*   row_ptr      = (int*)(ws + 140800000);              // (N+1) i32
  int*   cursor       = (int*)(ws + 141200128);              // N i32
  int*   row_cnt      = (int*)(ws + 141600128);              // N i32
  int*   bsums        = (int*)(ws + 142000128);              // 98 i32
  int*   offs         = (int*)(ws + 142000640);              // 98 i32
  int*   bcnt         = (int*)(ws + 142001152);              // NB i32
  int*   bucket_ptr   = (int*)(ws + 142004352);              // NB+1 i32
  int*   bcur         = (int*)(ws + 142007552);              // NB i32

  float* out0 = (float*)d_out;            // [N, 64] log_softmax(z)
  float* out1 = out0 + (size_t)NN * NC;   // [N, 128] fc3 output

  const int SCAN_BLKS = (NN + 1023) / 1024;  // 98

  // CSR build (two-phase multisplit)
  hipMemsetAsync(bcnt, 0, NB * sizeof(int), stream);
  bhist_k<<<NTILES, 256, 0, stream>>>(rows, bcnt);
  bscan_k<<<1, 256, 0, stream>>>(bcnt, bucket_ptr, bcur);
  phase1_bin<<<NTILES, 256, 0, stream>>>(rows, cols, vals, bcur, stage);
  rowhist_k<<<NB, 256, 0, stream>>>(stage, bucket_ptr, row_cnt);
  scanA_k<<<SCAN_BLKS, 256, 0, stream>>>(row_cnt, row_ptr, bsums);
  scanB_k<<<1, 128, 0, stream>>>(bsums, offs, SCAN_BLKS);
  scanC_k<<<SCAN_BLKS, 256, 0, stream>>>(row_ptr, cursor, offs);
  phase2_k<<<NB, 256, 0, stream>>>(stage, bucket_ptr, cursor, edge_s);

  // dense pipeline
  gemm1_mfma<<<dim3((NN + 127) / 128, 2), 256, 0, stream>>>(x, W1, t1b);
  spmm1_relu<<<NN / 4, 256, 0, stream>>>(t1b, edge_s, row_ptr, b1, hb);
  gemm2_mfma<<<(NN + 255) / 256, 256, 0, stream>>>(hb, W2, t2b);
  spmm2_fused<<<NN / 4, 256, 0, stream>>>(t2b, edge_s, row_ptr, b2, W3, b3, out0, out1);
}